// Round 8
// baseline (182.700 us; speedup 1.0000x reference)
//
#include <hip/hip_runtime.h>
#include <cstdint>
#include <cstddef>

#define B_  8
#define T_  1024
#define C_  768
#define H_  12
#define HD_ 64
#define K3_ 2304   // 3*C

typedef unsigned short u16;
typedef __attribute__((ext_vector_type(8))) short bf16x8;   // 8 bf16 (4 VGPRs)
typedef __attribute__((ext_vector_type(4))) float f32x4;    // 4 fp32 acc

#define MFMA __builtin_amdgcn_mfma_f32_16x16x32_bf16

__device__ __forceinline__ u16 f2bf(float f) {
    unsigned u = __builtin_bit_cast(unsigned, f);
    u += 0x7fffu + ((u >> 16) & 1u);           // round-to-nearest-even
    return (u16)(u >> 16);
}

// pack two fp32 -> bf16x2 dword (round-half-up; P>=0, feeds bf16 MFMA)
__device__ __forceinline__ unsigned pk2bf(float a, float b) {
    unsigned ua = __builtin_bit_cast(unsigned, a) + 0x8000u;
    unsigned ub = __builtin_bit_cast(unsigned, b) + 0x8000u;
    return (ua >> 16) | (ub & 0xffff0000u);
}

// async global->LDS, 16 B per lane. LDS dest = wave-uniform base + lane*16.
#define GLL16(gp, lp) __builtin_amdgcn_global_load_lds( \
    (__attribute__((address_space(1))) unsigned int*)(gp), \
    (__attribute__((address_space(3))) unsigned int*)(lp), 16, 0, 0)

// ---------------- prep: x->bf16 + both weight transposes, one kernel ----------------
__device__ __forceinline__ void tcvt_tile(const float* __restrict__ in, u16* __restrict__ out,
                                          int R, int Cc, int bx, int by, int tid, float* tile /*32x33*/) {
    int bc = bx * 32, br = by * 32;
    int tx = tid & 31, ty = tid >> 5;   // (32, 8)
    #pragma unroll
    for (int kk = 0; kk < 32; kk += 8)
        tile[(ty + kk) * 33 + tx] = in[(size_t)(br + ty + kk) * Cc + bc + tx];
    __syncthreads();
    #pragma unroll
    for (int kk = 0; kk < 32; kk += 8)
        out[(size_t)(bc + ty + kk) * R + br + tx] = f2bf(tile[tx * 33 + ty + kk]);
}

__global__ void prep(const float* __restrict__ x, u16* __restrict__ xb,
                     const float* __restrict__ wa, u16* __restrict__ wat,
                     const float* __restrict__ wp, u16* __restrict__ wpt) {
    __shared__ float tile[32 * 33];
    int bid = blockIdx.x, tid = threadIdx.x;
    if (bid < 6144) {                      // cvt: 8192*768/4 elements of float4
        int i = bid * 256 + tid;
        float4 v = ((const float4*)x)[i];
        ushort4 o;
        o.x = f2bf(v.x); o.y = f2bf(v.y); o.z = f2bf(v.z); o.w = f2bf(v.w);
        ((ushort4*)xb)[i] = o;
    } else if (bid < 6144 + 1728) {        // w_attn [768][2304] -> [2304][768]
        int b = bid - 6144;
        tcvt_tile(wa, wat, C_, K3_, b % 72, b / 72, tid, tile);
    } else {                               // w_proj [768][768] -> [768][768]^T
        int b = bid - 7872;
        tcvt_tile(wp, wpt, C_, C_, b % 24, b / 24, tid, tile);
    }
}

// ---------------- GEMM1: qkv = x @ w_attn + b_attn, scatter to q/k/v ----------------
// BK=32 double-buffered: prefetch tile it+1 into buf^1 while computing buf.
// LDS layout (u16): A[2][128][32] at 0/4096, B[2][128][32] at 8192/12288; Cs reuse.
__launch_bounds__(256)
__global__ void gemm_qkv(const u16* __restrict__ A, const u16* __restrict__ Bt,
                         const float* __restrict__ bias,
                         u16* __restrict__ q, u16* __restrict__ k, u16* __restrict__ v) {
    const int K = C_;
    __shared__ __align__(16) u16 SM[16896];
    u16 (*Cs)[132] = (u16(*)[132])SM;
    int tid = threadIdx.x;
    int id = blockIdx.x;
    int xcd = id & 7, jj = id >> 3;
    int m0 = (xcd * 8 + (jj & 7)) * 128;
    int n0 = (jj >> 3) * 128;
    int lane = tid & 63, wv = tid >> 6;
    int wm = (wv >> 1) * 64, wn = (wv & 1) * 64;
    int r16 = lane & 15, quad = lane >> 4;

    f32x4 acc[4][4] = {};
    // staging: row = tid>>2 (0..63 per round), global colblk XOR-swizzled
    int srow = tid >> 2;
    int g = (tid & 3) ^ ((tid >> 3) & 3);
    const u16* Ag = A  + (size_t)(m0 + srow) * K + g * 8;
    const u16* Bg = Bt + (size_t)(n0 + srow) * K + g * 8;
    int srd = (r16 >> 1) & 3;     // reader-side swizzle

    auto stage = [&](int kt, int b) {
        u16* Ab = SM + b * 4096 + tid * 8;
        u16* Bb = SM + 8192 + b * 4096 + tid * 8;
        GLL16(Ag + kt, Ab);
        GLL16(Ag + (size_t)64 * K + kt, Ab + 2048);
        GLL16(Bg + kt, Bb);
        GLL16(Bg + (size_t)64 * K + kt, Bb + 2048);
    };

    stage(0, 0);
    __syncthreads();
    for (int it = 0; it < K / 32; ++it) {
        int buf = it & 1;
        if (it + 1 < K / 32) stage((it + 1) * 32, buf ^ 1);
        bf16x8 af[4], bfr[4];
        #pragma unroll
        for (int i = 0; i < 4; i++)
            af[i]  = *(const bf16x8*)&SM[buf * 4096 + (wm + i * 16 + r16) * 32 + ((quad ^ srd) * 8)];
        #pragma unroll
        for (int j = 0; j < 4; j++)
            bfr[j] = *(const bf16x8*)&SM[8192 + buf * 4096 + (wn + j * 16 + r16) * 32 + ((quad ^ srd) * 8)];
        #pragma unroll
        for (int i = 0; i < 4; i++)
            #pragma unroll
            for (int j = 0; j < 4; j++)
                acc[i][j] = MFMA(af[i], bfr[j], acc[i][j], 0, 0, 0);
        __syncthreads();
    }

    int sec = n0 / C_;                 // block-uniform: 0=q, 1=k, 2=v
    int cc0 = n0 - sec * C_;
    int b = m0 >> 10, t0 = m0 & 1023;

    if (sec == 2) {
        #pragma unroll
        for (int i = 0; i < 4; i++) {
            #pragma unroll
            for (int j = 0; j < 4; j++) {
                int cc = cc0 + wn + j * 16 + r16;
                float bv = bias[2 * C_ + cc];
                int h = cc >> 6, hd = cc & 63;
                int t = t0 + wm + i * 16 + quad * 4;
                ushort4 ov;
                ov.x = f2bf(acc[i][j][0] + bv); ov.y = f2bf(acc[i][j][1] + bv);
                ov.z = f2bf(acc[i][j][2] + bv); ov.w = f2bf(acc[i][j][3] + bv);
                *(ushort4*)(v + (((size_t)b * H_ + h) * HD_ + hd) * T_ + t) = ov;
            }
        }
    } else {
        float scale = (sec == 0) ? 0.125f : 1.0f;
        u16* dst = (sec == 0) ? q : k;
        #pragma unroll
        for (int i = 0; i < 4; i++)
            #pragma unroll
            for (int j = 0; j < 4; j++) {
                int col = wn + j * 16 + r16;
                float bv = bias[sec * C_ + cc0 + col];
                #pragma unroll
                for (int r = 0; r < 4; r++)
                    Cs[wm + i * 16 + quad * 4 + r][col] = f2bf((acc[i][j][r] + bv) * scale);
            }
        __syncthreads();
        int h0 = cc0 >> 6;
        int rsel = tid >> 4;
        int hs = (tid >> 3) & 1;
        int c8 = (tid & 7) * 8;
        #pragma unroll
        for (int p = 0; p < 8; p++) {
            int rl = p * 16 + rsel;
            uint4 val = *(const uint4*)&Cs[rl][hs * 64 + c8];
            *(uint4*)(dst + (((size_t)b * H_ + h0 + hs) * T_ + t0 + rl) * HD_ + c8) = val;
        }
    }
}

// ---------------- GEMM2: out = y @ w_proj + b_proj (fp32 out) ----------------
__launch_bounds__(256)
__global__ void gemm_proj(const u16* __restrict__ A, const u16* __restrict__ Bt,
                          const float* __restrict__ bias, float* __restrict__ out) {
    const int K = C_, N = C_;
    __shared__ __align__(16) u16 SM[16384];
    int tid = threadIdx.x;
    int id = blockIdx.x;
    int xcd = id & 7, jj = id >> 3;
    int m0 = (xcd * 8 + (jj & 7)) * 128;
    int n0 = (jj >> 3) * 128;
    int lane = tid & 63, wv = tid >> 6;
    int wm = (wv >> 1) * 64, wn = (wv & 1) * 64;
    int r16 = lane & 15, quad = lane >> 4;

    f32x4 acc[4][4] = {};
    int srow = tid >> 2;
    int g = (tid & 3) ^ ((tid >> 3) & 3);
    const u16* Ag = A  + (size_t)(m0 + srow) * K + g * 8;
    const u16* Bg = Bt + (size_t)(n0 + srow) * K + g * 8;
    int srd = (r16 >> 1) & 3;

    auto stage = [&](int kt, int b) {
        u16* Ab = SM + b * 4096 + tid * 8;
        u16* Bb = SM + 8192 + b * 4096 + tid * 8;
        GLL16(Ag + kt, Ab);
        GLL16(Ag + (size_t)64 * K + kt, Ab + 2048);
        GLL16(Bg + kt, Bb);
        GLL16(Bg + (size_t)64 * K + kt, Bb + 2048);
    };

    stage(0, 0);
    __syncthreads();
    for (int it = 0; it < K / 32; ++it) {
        int buf = it & 1;
        if (it + 1 < K / 32) stage((it + 1) * 32, buf ^ 1);
        bf16x8 af[4], bfr[4];
        #pragma unroll
        for (int i = 0; i < 4; i++)
            af[i]  = *(const bf16x8*)&SM[buf * 4096 + (wm + i * 16 + r16) * 32 + ((quad ^ srd) * 8)];
        #pragma unroll
        for (int j = 0; j < 4; j++)
            bfr[j] = *(const bf16x8*)&SM[8192 + buf * 4096 + (wn + j * 16 + r16) * 32 + ((quad ^ srd) * 8)];
        #pragma unroll
        for (int i = 0; i < 4; i++)
            #pragma unroll
            for (int j = 0; j < 4; j++)
                acc[i][j] = MFMA(af[i], bfr[j], acc[i][j], 0, 0, 0);
        __syncthreads();
    }

    #pragma unroll
    for (int i = 0; i < 4; i++) {
        #pragma unroll
        for (int j = 0; j < 4; j++) {
            int gn = n0 + wn + j * 16 + r16;
            float bv = bias[gn];
            #pragma unroll
            for (int r = 0; r < 4; r++) {
                int gm = m0 + wm + i * 16 + quad * 4 + r;
                out[(size_t)gm * N + gn] = acc[i][j][r] + bv;
            }
        }
    }
}

// ---------------- Flash attention: LDS-staged K/V (double-buffered), paired q-tiles ----
__launch_bounds__(256, 2)
__global__ void attn(const u16* __restrict__ q, const u16* __restrict__ k,
                     const u16* __restrict__ v, u16* __restrict__ y) {
    __shared__ __align__(16) u16 Kb[2][64][64];     // [buf][key][hd]
    __shared__ __align__(16) u16 Vb[2][64][64];     // [buf][hd][key]
    __shared__ __align__(16) u16 P[4][2][16][72];   // per-wave, per-tile P^T
    int tid = threadIdx.x, lane = tid & 63, w = tid >> 6;
    int r16 = lane & 15, quad = lane >> 4;
    int id = blockIdx.x;
    int bh = id % 96;             // same head -> ids 96 apart -> same XCD (96%8==0)
    int bi = id / 96;             // 0..7; bi=0 (longest, n64=16) dispatched first
    int b = bh / H_, h = bh - b * H_;
    int x = bi * 4 + w;           // 0..31
    int t_lo = x, t_hi = 63 - x;
    int qb_lo = t_lo * 16, qb_hi = t_hi * 16;
    const u16* qh = q + (size_t)bh * T_ * HD_;
    const u16* kh = k + (size_t)bh * T_ * HD_;
    const u16* vh = v + (size_t)bh * HD_ * T_;   // [HD][T]

    bf16x8 ql0 = *(const bf16x8*)(qh + (size_t)(qb_lo + r16) * HD_ + quad * 8);
    bf16x8 ql1 = *(const bf16x8*)(qh + (size_t)(qb_lo + r16) * HD_ + 32 + quad * 8);
    bf16x8 qh0 = *(const bf16x8*)(qh + (size_t)(qb_hi + r16) * HD_ + quad * 8);
    bf16x8 qh1 = *(const bf16x8*)(qh + (size_t)(qb_hi + r16) * HD_ + 32 + quad * 8);

    f32x4 oL[4] = {}, oH[4] = {};
    float lL = 0.f, lH = 0.f;
    int qyL = qb_lo + r16, qyH = qb_hi + r16;
    int ilo_last = bi;                                   // block-uniform
    int n64 = __builtin_amdgcn_readfirstlane(16 - bi);   // block-uniform

    int srow = lane >> 3;         // 0..7
    int scb  = (lane & 7) ^ srow; // XOR-swizzled global colblk
    const u16* kst = kh + (size_t)(w * 16 + srow) * HD_ + scb * 8;
    const u16* vst = vh + (size_t)(w * 16 + srow) * T_ + scb * 8;
    int swz = (r16 & 7);          // reader-side swizzle

    {
        #pragma unroll
        for (int s2 = 0; s2 < 2; s2++) {
            GLL16(kst + (size_t)(s2 * 8) * HD_, &Kb[0][w * 16 + s2 * 8][0] + lane * 8);
            GLL16(vst + (size_t)(s2 * 8) * T_,  &Vb[0][w * 16 + s2 * 8][0] + lane * 8);
        }
    }
    __syncthreads();

    for (int it = 0; it < n64; ++it) {
        int kv0 = it * 64;
        int buf = it & 1;
        bool lo_on = (it <= ilo_last);
        if (it + 1 < n64) {
            int kvn = kv0 + 64;
            #pragma unroll
            for (int s2 = 0; s2 < 2; s2++) {
                GLL16(kst + (size_t)(kvn + s2 * 8) * HD_, &Kb[buf ^ 1][w * 16 + s2 * 8][0] + lane * 8);
                GLL16(vst + (size_t)(s2 * 8) * T_ + kvn,  &Vb[buf ^ 1][w * 16 + s2 * 8][0] + lane * 8);
            }
        }
        bf16x8 kf[4][2];
        #pragma unroll
        for (int n = 0; n < 4; n++)
            #pragma unroll
            for (int c = 0; c < 2; c++)
                kf[n][c] = *(const bf16x8*)&Kb[buf][n * 16 + r16][((c * 4 + quad) ^ swz) * 8];
        f32x4 sH[4] = {};
        #pragma unroll
        for (int n = 0; n < 4; n++) {
            sH[n] = MFMA(kf[n][0], qh0, sH[n], 0, 0, 0);
            sH[n] = MFMA(kf[n][1], qh1, sH[n], 0, 0, 0);
        }
        if (it == n64 - 1) {
            #pragma unroll
            for (int n = 0; n < 4; n++)
                #pragma unroll
                for (int r = 0; r < 4; r++)
                    if (kv0 + n * 16 + quad * 4 + r > qyH) sH[n][r] = -1e30f;
        }
        #pragma unroll
        for (int n = 0; n < 4; n++) {
            float p0 = __expf(sH[n][0]);
            float p1 = __expf(sH[n][1]);
            float p2 = __expf(sH[n][2]);
            float p3 = __expf(sH[n][3]);
            lH += (p0 + p1) + (p2 + p3);
            uint2 pd; pd.x = pk2bf(p0, p1); pd.y = pk2bf(p2, p3);
            *(uint2*)&P[w][1][r16][n * 16 + quad * 4] = pd;
        }
        if (lo_on) {
            f32x4 sL[4] = {};
            #pragma unroll
            for (int n = 0; n < 4; n++) {
                sL[n] = MFMA(kf[n][0], ql0, sL[n], 0, 0, 0);
                sL[n] = MFMA(kf[n][1], ql1, sL[n], 0, 0, 0);
            }
            if (it == ilo_last) {
                #pragma unroll
                for (int n = 0; n < 4; n++)
                    #pragma unroll
                    for (int r = 0; r < 4; r++)
                        if (kv0 + n * 16 + quad * 4 + r > qyL) sL[n][r] = -1e30f;
            }
            #pragma unroll
            for (int n = 0; n < 4; n++) {
                float p0 = __expf(sL[n][0]);
                float p1 = __expf(sL[n][1]);
                float p2 = __expf(sL[n][2]);
                float p3 = __expf(sL[n][3]);
                lL += (p0 + p1) + (p2 + p3);
                uint2 pd; pd.x = pk2bf(p0, p1); pd.y = pk2bf(p2, p3);
                *(uint2*)&P[w][0][r16][n * 16 + quad * 4] = pd;
            }
        }
        bf16x8 vf[4][2];
        #pragma unroll
        for (int j = 0; j < 4; j++)
            #pragma unroll
            for (int c = 0; c < 2; c++)
                vf[j][c] = *(const bf16x8*)&Vb[buf][j * 16 + r16][((c * 4 + quad) ^ swz) * 8];
        #pragma unroll
        for (int c = 0; c < 2; c++) {
            bf16x8 pfH = *(const bf16x8*)&P[w][1][r16][c * 32 + quad * 8];
            #pragma unroll
            for (int j = 0; j < 4; j++)
                oH[j] = MFMA(vf[j][c], pfH, oH[j], 0, 0, 0);
        }
        if (lo_on) {
            #pragma unroll
            for (int c = 0; c < 2; c++) {
                bf16x8 pfL = *(const bf16x8*)&P[w][0][r16][c * 32 + quad * 8];
                #pragma unroll
                for (int j = 0; j < 4; j++)
                    oL[j] = MFMA(vf[j][c], pfL, oL[j], 0, 0, 0);
            }
        }
        __syncthreads();
    }

    lH += __shfl_xor(lH, 16, 64);
    lH += __shfl_xor(lH, 32, 64);
    lL += __shfl_xor(lL, 16, 64);
    lL += __shfl_xor(lL, 32, 64);
    float invH = 1.f / lH, invL = 1.f / lL;
    int tqH = qb_hi + r16, tqL = qb_lo + r16;
    #pragma unroll
    for (int j = 0; j < 4; j++) {
        ushort4 ovH, ovL;
        ovH.x = f2bf(oH[j][0] * invH); ovH.y = f2bf(oH[j][1] * invH);
        ovH.z = f2bf(oH[j][2] * invH); ovH.w = f2bf(oH[j][3] * invH);
        ovL.x = f2bf(oL[j][0] * invL); ovL.y = f2bf(oL[j][1] * invL);
        ovL.z = f2bf(oL[j][2] * invL); ovL.w = f2bf(oL[j][3] * invL);
        *(ushort4*)(y + ((size_t)b * T_ + tqH) * C_ + h * 64 + j * 16 + quad * 4) = ovH;
        *(ushort4*)(y + ((size_t)b * T_ + tqL) * C_ + h * 64 + j * 16 + quad * 4) = ovL;
    }
}

extern "C" void kernel_launch(void* const* d_in, const int* in_sizes, int n_in,
                              void* d_out, int out_size, void* d_ws, size_t ws_size,
                              hipStream_t stream) {
    const float* x      = (const float*)d_in[0];
    const float* w_attn = (const float*)d_in[1];
    const float* b_attn = (const float*)d_in[2];
    const float* w_proj = (const float*)d_in[3];
    const float* b_proj = (const float*)d_in[4];
    float* out = (float*)d_out;

    char* ws = (char*)d_ws;
    size_t off = 0;
    auto alloc = [&](size_t bytes) {
        void* p = ws + off;
        off += (bytes + 255) & ~(size_t)255;
        return p;
    };
    const size_t M = (size_t)B_ * T_;                    // 8192
    u16* x_bf = (u16*)alloc(M * C_ * 2);                 // [8192][768]
    u16* wat  = (u16*)alloc((size_t)K3_ * C_ * 2);       // [2304][768]
    u16* wpt  = (u16*)alloc((size_t)C_ * C_ * 2);        // [768][768]
    u16* qb   = (u16*)alloc((size_t)B_ * H_ * T_ * HD_ * 2);
    u16* kb   = (u16*)alloc((size_t)B_ * H_ * T_ * HD_ * 2);
    u16* vb   = (u16*)alloc((size_t)B_ * H_ * T_ * HD_ * 2);
    u16* yb   = (u16*)alloc(M * C_ * 2);                 // [8192][768]

    prep<<<6144 + 1728 + 576, 256, 0, stream>>>(x, x_bf, w_attn, wat, w_proj, wpt);
    gemm_qkv<<<8 * 144, 256, 0, stream>>>(x_bf, wat, b_attn, qb, kb, vb);
    attn<<<8 * 96, 256, 0, stream>>>(qb, kb, vb, yb);
    gemm_proj<<<8 * 48, 256, 0, stream>>>(yb, wpt, b_proj, out);
}

// Round 9
// 176.359 us; speedup vs baseline: 1.0360x; 1.0360x over previous
//
#include <hip/hip_runtime.h>
#include <cstdint>
#include <cstddef>

#define B_  8
#define T_  1024
#define C_  768
#define H_  12
#define HD_ 64
#define K3_ 2304   // 3*C

typedef unsigned short u16;
typedef __attribute__((ext_vector_type(8))) short bf16x8;   // 8 bf16 (4 VGPRs)
typedef __attribute__((ext_vector_type(4))) float f32x4;    // 4 fp32 acc

#define MFMA __builtin_amdgcn_mfma_f32_16x16x32_bf16

__device__ __forceinline__ u16 f2bf(float f) {
    unsigned u = __builtin_bit_cast(unsigned, f);
    u += 0x7fffu + ((u >> 16) & 1u);           // round-to-nearest-even
    return (u16)(u >> 16);
}

// pack two fp32 -> bf16x2 dword (round-half-up; P>=0, feeds bf16 MFMA)
__device__ __forceinline__ unsigned pk2bf(float a, float b) {
    unsigned ua = __builtin_bit_cast(unsigned, a) + 0x8000u;
    unsigned ub = __builtin_bit_cast(unsigned, b) + 0x8000u;
    return (ua >> 16) | (ub & 0xffff0000u);
}

// async global->LDS, 16 B per lane. LDS dest = wave-uniform base + lane*16.
#define GLL16(gp, lp) __builtin_amdgcn_global_load_lds( \
    (__attribute__((address_space(1))) unsigned int*)(gp), \
    (__attribute__((address_space(3))) unsigned int*)(lp), 16, 0, 0)

// ---------------- prep: x->bf16 + both weight transposes, one kernel ----------------
__device__ __forceinline__ void tcvt_tile(const float* __restrict__ in, u16* __restrict__ out,
                                          int R, int Cc, int bx, int by, int tid, float* tile /*32x33*/) {
    int bc = bx * 32, br = by * 32;
    int tx = tid & 31, ty = tid >> 5;   // (32, 8)
    #pragma unroll
    for (int kk = 0; kk < 32; kk += 8)
        tile[(ty + kk) * 33 + tx] = in[(size_t)(br + ty + kk) * Cc + bc + tx];
    __syncthreads();
    #pragma unroll
    for (int kk = 0; kk < 32; kk += 8)
        out[(size_t)(bc + ty + kk) * R + br + tx] = f2bf(tile[tx * 33 + ty + kk]);
}

__global__ void prep(const float* __restrict__ x, u16* __restrict__ xb,
                     const float* __restrict__ wa, u16* __restrict__ wat,
                     const float* __restrict__ wp, u16* __restrict__ wpt) {
    __shared__ float tile[32 * 33];
    int bid = blockIdx.x, tid = threadIdx.x;
    if (bid < 6144) {                      // cvt: 8192*768/4 elements of float4
        int i = bid * 256 + tid;
        float4 v = ((const float4*)x)[i];
        ushort4 o;
        o.x = f2bf(v.x); o.y = f2bf(v.y); o.z = f2bf(v.z); o.w = f2bf(v.w);
        ((ushort4*)xb)[i] = o;
    } else if (bid < 6144 + 1728) {        // w_attn [768][2304] -> [2304][768]
        int b = bid - 6144;
        tcvt_tile(wa, wat, C_, K3_, b % 72, b / 72, tid, tile);
    } else {                               // w_proj [768][768] -> [768][768]^T
        int b = bid - 7872;
        tcvt_tile(wp, wpt, C_, C_, b % 24, b / 24, tid, tile);
    }
}

// ---------------- GEMM1: qkv = x @ w_attn + b_attn, scatter to q/k/v ----------------
// BK=64, DOUBLE-BUFFERED (A/B 2x16KB each = 64KB LDS): prefetch tile it+1 at iter
// start, one barrier per iter at iter end -> the vmcnt drain waits on loads issued
// a full 32-MFMA compute window earlier. XOR-swizzled staging (measured 0 conflicts).
__launch_bounds__(256)
__global__ void gemm_qkv(const u16* __restrict__ A, const u16* __restrict__ Bt,
                         const float* __restrict__ bias,
                         u16* __restrict__ q, u16* __restrict__ k, u16* __restrict__ v) {
    const int K = C_;
    __shared__ __align__(16) u16 SM[32768];      // A0@0 A1@8192 B0@16384 B1@24576 (u16)
    u16 (*Cs)[132] = (u16(*)[132])SM;            // epilogue reuse
    int tid = threadIdx.x;
    int id = blockIdx.x;
    int xcd = id & 7, jj = id >> 3;
    int m0 = (xcd * 8 + (jj & 7)) * 128;
    int n0 = (jj >> 3) * 128;
    int lane = tid & 63, wv = tid >> 6;
    int wm = (wv >> 1) * 64, wn = (wv & 1) * 64;
    int r16 = lane & 15, quad = lane >> 4;

    f32x4 acc[4][4] = {};
    int srow = tid >> 3;                        // 0..31
    int gblk = (tid & 7) ^ (srow & 7);          // XOR-swizzled global 16B-block
    const u16* Ag = A  + (size_t)(m0 + srow) * K + gblk * 8;
    const u16* Bg = Bt + (size_t)(n0 + srow) * K + gblk * 8;
    int sw = r16 & 7;

    auto stage = [&](int kt, int b) {
        u16* Ab = SM + b * 8192 + tid * 8;
        u16* Bb = SM + 16384 + b * 8192 + tid * 8;
        #pragma unroll
        for (int s = 0; s < 4; s++) {
            GLL16(Ag + (size_t)(s * 32) * K + kt, Ab + s * 2048);
            GLL16(Bg + (size_t)(s * 32) * K + kt, Bb + s * 2048);
        }
    };

    stage(0, 0);
    __syncthreads();
    for (int it = 0; it < K / 64; ++it) {
        int buf = it & 1;
        if (it + 1 < K / 64) stage((it + 1) * 64, buf ^ 1);
        #pragma unroll
        for (int kk = 0; kk < 2; kk++) {
            bf16x8 af[4], bfr[4];
            #pragma unroll
            for (int i = 0; i < 4; i++)
                af[i]  = *(const bf16x8*)&SM[buf * 8192 + (wm + i * 16 + r16) * 64 + ((kk * 4 + quad) ^ sw) * 8];
            #pragma unroll
            for (int j = 0; j < 4; j++)
                bfr[j] = *(const bf16x8*)&SM[16384 + buf * 8192 + (wn + j * 16 + r16) * 64 + ((kk * 4 + quad) ^ sw) * 8];
            #pragma unroll
            for (int i = 0; i < 4; i++)
                #pragma unroll
                for (int j = 0; j < 4; j++)
                    acc[i][j] = MFMA(af[i], bfr[j], acc[i][j], 0, 0, 0);
        }
        __syncthreads();
    }

    int sec = n0 / C_;                 // block-uniform: 0=q, 1=k, 2=v
    int cc0 = n0 - sec * C_;
    int b = m0 >> 10, t0 = m0 & 1023;

    if (sec == 2) {
        #pragma unroll
        for (int i = 0; i < 4; i++) {
            #pragma unroll
            for (int j = 0; j < 4; j++) {
                int cc = cc0 + wn + j * 16 + r16;
                float bv = bias[2 * C_ + cc];
                int h = cc >> 6, hd = cc & 63;
                int t = t0 + wm + i * 16 + quad * 4;
                ushort4 ov;
                ov.x = f2bf(acc[i][j][0] + bv); ov.y = f2bf(acc[i][j][1] + bv);
                ov.z = f2bf(acc[i][j][2] + bv); ov.w = f2bf(acc[i][j][3] + bv);
                *(ushort4*)(v + (((size_t)b * H_ + h) * HD_ + hd) * T_ + t) = ov;
            }
        }
    } else {
        float scale = (sec == 0) ? 0.125f : 1.0f;
        u16* dst = (sec == 0) ? q : k;
        #pragma unroll
        for (int i = 0; i < 4; i++)
            #pragma unroll
            for (int j = 0; j < 4; j++) {
                int col = wn + j * 16 + r16;
                float bv = bias[sec * C_ + cc0 + col];
                #pragma unroll
                for (int r = 0; r < 4; r++)
                    Cs[wm + i * 16 + quad * 4 + r][col] = f2bf((acc[i][j][r] + bv) * scale);
            }
        __syncthreads();
        int h0 = cc0 >> 6;
        int rsel = tid >> 4;
        int hs = (tid >> 3) & 1;
        int c8 = (tid & 7) * 8;
        #pragma unroll
        for (int p = 0; p < 8; p++) {
            int rl = p * 16 + rsel;
            uint4 val = *(const uint4*)&Cs[rl][hs * 64 + c8];
            *(uint4*)(dst + (((size_t)b * H_ + h0 + hs) * T_ + t0 + rl) * HD_ + c8) = val;
        }
    }
}

// ---------------- GEMM2: out = y @ w_proj + b_proj (fp32 out) ----------------
__launch_bounds__(256)
__global__ void gemm_proj(const u16* __restrict__ A, const u16* __restrict__ Bt,
                          const float* __restrict__ bias, float* __restrict__ out) {
    const int K = C_, N = C_;
    __shared__ __align__(16) u16 SM[32768];
    int tid = threadIdx.x;
    int id = blockIdx.x;
    int xcd = id & 7, jj = id >> 3;
    int m0 = (xcd * 8 + (jj & 7)) * 128;
    int n0 = (jj >> 3) * 128;
    int lane = tid & 63, wv = tid >> 6;
    int wm = (wv >> 1) * 64, wn = (wv & 1) * 64;
    int r16 = lane & 15, quad = lane >> 4;

    f32x4 acc[4][4] = {};
    int srow = tid >> 3;
    int gblk = (tid & 7) ^ (srow & 7);
    const u16* Ag = A  + (size_t)(m0 + srow) * K + gblk * 8;
    const u16* Bg = Bt + (size_t)(n0 + srow) * K + gblk * 8;
    int sw = r16 & 7;

    auto stage = [&](int kt, int b) {
        u16* Ab = SM + b * 8192 + tid * 8;
        u16* Bb = SM + 16384 + b * 8192 + tid * 8;
        #pragma unroll
        for (int s = 0; s < 4; s++) {
            GLL16(Ag + (size_t)(s * 32) * K + kt, Ab + s * 2048);
            GLL16(Bg + (size_t)(s * 32) * K + kt, Bb + s * 2048);
        }
    };

    stage(0, 0);
    __syncthreads();
    for (int it = 0; it < K / 64; ++it) {
        int buf = it & 1;
        if (it + 1 < K / 64) stage((it + 1) * 64, buf ^ 1);
        #pragma unroll
        for (int kk = 0; kk < 2; kk++) {
            bf16x8 af[4], bfr[4];
            #pragma unroll
            for (int i = 0; i < 4; i++)
                af[i]  = *(const bf16x8*)&SM[buf * 8192 + (wm + i * 16 + r16) * 64 + ((kk * 4 + quad) ^ sw) * 8];
            #pragma unroll
            for (int j = 0; j < 4; j++)
                bfr[j] = *(const bf16x8*)&SM[16384 + buf * 8192 + (wn + j * 16 + r16) * 64 + ((kk * 4 + quad) ^ sw) * 8];
            #pragma unroll
            for (int i = 0; i < 4; i++)
                #pragma unroll
                for (int j = 0; j < 4; j++)
                    acc[i][j] = MFMA(af[i], bfr[j], acc[i][j], 0, 0, 0);
        }
        __syncthreads();
    }

    #pragma unroll
    for (int i = 0; i < 4; i++) {
        #pragma unroll
        for (int j = 0; j < 4; j++) {
            int gn = n0 + wn + j * 16 + r16;
            float bv = bias[gn];
            #pragma unroll
            for (int r = 0; r < 4; r++) {
                int gm = m0 + wm + i * 16 + quad * 4 + r;
                out[(size_t)gm * N + gn] = acc[i][j][r] + bv;
            }
        }
    }
}

// ---------------- Flash attention: LDS-staged K/V (double-buffered), paired q-tiles ----
__launch_bounds__(256, 2)
__global__ void attn(const u16* __restrict__ q, const u16* __restrict__ k,
                     const u16* __restrict__ v, u16* __restrict__ y) {
    __shared__ __align__(16) u16 Kb[2][64][64];     // [buf][key][hd]
    __shared__ __align__(16) u16 Vb[2][64][64];     // [buf][hd][key]
    __shared__ __align__(16) u16 P[4][2][16][72];   // per-wave, per-tile P^T
    int tid = threadIdx.x, lane = tid & 63, w = tid >> 6;
    int r16 = lane & 15, quad = lane >> 4;
    int id = blockIdx.x;
    int bh = id % 96;             // same head -> ids 96 apart -> same XCD (96%8==0)
    int bi = id / 96;             // 0..7; bi=0 (longest, n64=16) dispatched first
    int b = bh / H_, h = bh - b * H_;
    int x = bi * 4 + w;           // 0..31
    int t_lo = x, t_hi = 63 - x;
    int qb_lo = t_lo * 16, qb_hi = t_hi * 16;
    const u16* qh = q + (size_t)bh * T_ * HD_;
    const u16* kh = k + (size_t)bh * T_ * HD_;
    const u16* vh = v + (size_t)bh * HD_ * T_;   // [HD][T]

    bf16x8 ql0 = *(const bf16x8*)(qh + (size_t)(qb_lo + r16) * HD_ + quad * 8);
    bf16x8 ql1 = *(const bf16x8*)(qh + (size_t)(qb_lo + r16) * HD_ + 32 + quad * 8);
    bf16x8 qh0 = *(const bf16x8*)(qh + (size_t)(qb_hi + r16) * HD_ + quad * 8);
    bf16x8 qh1 = *(const bf16x8*)(qh + (size_t)(qb_hi + r16) * HD_ + 32 + quad * 8);

    f32x4 oL[4] = {}, oH[4] = {};
    float lL = 0.f, lH = 0.f;
    int qyL = qb_lo + r16, qyH = qb_hi + r16;
    int ilo_last = bi;                                   // block-uniform
    int n64 = __builtin_amdgcn_readfirstlane(16 - bi);   // block-uniform

    int srow = lane >> 3;         // 0..7
    int scb  = (lane & 7) ^ srow; // XOR-swizzled global colblk
    const u16* kst = kh + (size_t)(w * 16 + srow) * HD_ + scb * 8;
    const u16* vst = vh + (size_t)(w * 16 + srow) * T_ + scb * 8;
    int swz = (r16 & 7);          // reader-side swizzle

    {
        #pragma unroll
        for (int s2 = 0; s2 < 2; s2++) {
            GLL16(kst + (size_t)(s2 * 8) * HD_, &Kb[0][w * 16 + s2 * 8][0] + lane * 8);
            GLL16(vst + (size_t)(s2 * 8) * T_,  &Vb[0][w * 16 + s2 * 8][0] + lane * 8);
        }
    }
    __syncthreads();

    for (int it = 0; it < n64; ++it) {
        int kv0 = it * 64;
        int buf = it & 1;
        bool lo_on = (it <= ilo_last);
        if (it + 1 < n64) {
            int kvn = kv0 + 64;
            #pragma unroll
            for (int s2 = 0; s2 < 2; s2++) {
                GLL16(kst + (size_t)(kvn + s2 * 8) * HD_, &Kb[buf ^ 1][w * 16 + s2 * 8][0] + lane * 8);
                GLL16(vst + (size_t)(s2 * 8) * T_ + kvn,  &Vb[buf ^ 1][w * 16 + s2 * 8][0] + lane * 8);
            }
        }
        bf16x8 kf[4][2];
        #pragma unroll
        for (int n = 0; n < 4; n++)
            #pragma unroll
            for (int c = 0; c < 2; c++)
                kf[n][c] = *(const bf16x8*)&Kb[buf][n * 16 + r16][((c * 4 + quad) ^ swz) * 8];
        f32x4 sH[4] = {};
        #pragma unroll
        for (int n = 0; n < 4; n++) {
            sH[n] = MFMA(kf[n][0], qh0, sH[n], 0, 0, 0);
            sH[n] = MFMA(kf[n][1], qh1, sH[n], 0, 0, 0);
        }
        if (it == n64 - 1) {
            #pragma unroll
            for (int n = 0; n < 4; n++)
                #pragma unroll
                for (int r = 0; r < 4; r++)
                    if (kv0 + n * 16 + quad * 4 + r > qyH) sH[n][r] = -1e30f;
        }
        #pragma unroll
        for (int n = 0; n < 4; n++) {
            float p0 = __expf(sH[n][0]);
            float p1 = __expf(sH[n][1]);
            float p2 = __expf(sH[n][2]);
            float p3 = __expf(sH[n][3]);
            lH += (p0 + p1) + (p2 + p3);
            uint2 pd; pd.x = pk2bf(p0, p1); pd.y = pk2bf(p2, p3);
            *(uint2*)&P[w][1][r16][n * 16 + quad * 4] = pd;
        }
        if (lo_on) {
            f32x4 sL[4] = {};
            #pragma unroll
            for (int n = 0; n < 4; n++) {
                sL[n] = MFMA(kf[n][0], ql0, sL[n], 0, 0, 0);
                sL[n] = MFMA(kf[n][1], ql1, sL[n], 0, 0, 0);
            }
            if (it == ilo_last) {
                #pragma unroll
                for (int n = 0; n < 4; n++)
                    #pragma unroll
                    for (int r = 0; r < 4; r++)
                        if (kv0 + n * 16 + quad * 4 + r > qyL) sL[n][r] = -1e30f;
            }
            #pragma unroll
            for (int n = 0; n < 4; n++) {
                float p0 = __expf(sL[n][0]);
                float p1 = __expf(sL[n][1]);
                float p2 = __expf(sL[n][2]);
                float p3 = __expf(sL[n][3]);
                lL += (p0 + p1) + (p2 + p3);
                uint2 pd; pd.x = pk2bf(p0, p1); pd.y = pk2bf(p2, p3);
                *(uint2*)&P[w][0][r16][n * 16 + quad * 4] = pd;
            }
        }
        bf16x8 vf[4][2];
        #pragma unroll
        for (int j = 0; j < 4; j++)
            #pragma unroll
            for (int c = 0; c < 2; c++)
                vf[j][c] = *(const bf16x8*)&Vb[buf][j * 16 + r16][((c * 4 + quad) ^ swz) * 8];
        #pragma unroll
        for (int c = 0; c < 2; c++) {
            bf16x8 pfH = *(const bf16x8*)&P[w][1][r16][c * 32 + quad * 8];
            #pragma unroll
            for (int j = 0; j < 4; j++)
                oH[j] = MFMA(vf[j][c], pfH, oH[j], 0, 0, 0);
        }
        if (lo_on) {
            #pragma unroll
            for (int c = 0; c < 2; c++) {
                bf16x8 pfL = *(const bf16x8*)&P[w][0][r16][c * 32 + quad * 8];
                #pragma unroll
                for (int j = 0; j < 4; j++)
                    oL[j] = MFMA(vf[j][c], pfL, oL[j], 0, 0, 0);
            }
        }
        __syncthreads();
    }

    lH += __shfl_xor(lH, 16, 64);
    lH += __shfl_xor(lH, 32, 64);
    lL += __shfl_xor(lL, 16, 64);
    lL += __shfl_xor(lL, 32, 64);
    float invH = 1.f / lH, invL = 1.f / lL;
    int tqH = qb_hi + r16, tqL = qb_lo + r16;
    #pragma unroll
    for (int j = 0; j < 4; j++) {
        ushort4 ovH, ovL;
        ovH.x = f2bf(oH[j][0] * invH); ovH.y = f2bf(oH[j][1] * invH);
        ovH.z = f2bf(oH[j][2] * invH); ovH.w = f2bf(oH[j][3] * invH);
        ovL.x = f2bf(oL[j][0] * invL); ovL.y = f2bf(oL[j][1] * invL);
        ovL.z = f2bf(oL[j][2] * invL); ovL.w = f2bf(oL[j][3] * invL);
        *(ushort4*)(y + ((size_t)b * T_ + tqH) * C_ + h * 64 + j * 16 + quad * 4) = ovH;
        *(ushort4*)(y + ((size_t)b * T_ + tqL) * C_ + h * 64 + j * 16 + quad * 4) = ovL;
    }
}

extern "C" void kernel_launch(void* const* d_in, const int* in_sizes, int n_in,
                              void* d_out, int out_size, void* d_ws, size_t ws_size,
                              hipStream_t stream) {
    const float* x      = (const float*)d_in[0];
    const float* w_attn = (const float*)d_in[1];
    const float* b_attn = (const float*)d_in[2];
    const float* w_proj = (const float*)d_in[3];
    const float* b_proj = (const float*)d_in[4];
    float* out = (float*)d_out;

    char* ws = (char*)d_ws;
    size_t off = 0;
    auto alloc = [&](size_t bytes) {
        void* p = ws + off;
        off += (bytes + 255) & ~(size_t)255;
        return p;
    };
    const size_t M = (size_t)B_ * T_;                    // 8192
    u16* x_bf = (u16*)alloc(M * C_ * 2);                 // [8192][768]
    u16* wat  = (u16*)alloc((size_t)K3_ * C_ * 2);       // [2304][768]
    u16* wpt  = (u16*)alloc((size_t)C_ * C_ * 2);        // [768][768]
    u16* qb   = (u16*)alloc((size_t)B_ * H_ * T_ * HD_ * 2);
    u16* kb   = (u16*)alloc((size_t)B_ * H_ * T_ * HD_ * 2);
    u16* vb   = (u16*)alloc((size_t)B_ * H_ * T_ * HD_ * 2);
    u16* yb   = (u16*)alloc(M * C_ * 2);                 // [8192][768]

    prep<<<6144 + 1728 + 576, 256, 0, stream>>>(x, x_bf, w_attn, wat, w_proj, wpt);
    gemm_qkv<<<8 * 144, 256, 0, stream>>>(x_bf, wat, b_attn, qb, kb, vb);
    attn<<<8 * 96, 256, 0, stream>>>(qb, kb, vb, yb);
    gemm_proj<<<8 * 48, 256, 0, stream>>>(yb, wpt, b_proj, out);
}